// Round 15
// baseline (126.061 us; speedup 1.0000x reference)
//
#include <hip/hip_runtime.h>
#include <hip/hip_bf16.h>

using f32x4 = __attribute__((ext_vector_type(4))) float;
using s16x8 = __attribute__((ext_vector_type(8))) short;

#define MFMA16x16x32(a, b, c) __builtin_amdgcn_mfma_f32_16x16x32_bf16((a), (b), (c), 0, 0, 0)

#define AS_G(p) ((const __attribute__((address_space(1))) void*)(p))
#define AS_L(p) ((__attribute__((address_space(3))) void*)(p))

// barrier with LDS-visibility only: does NOT drain vmcnt
#define BARRIER_LGKM() do { \
    asm volatile("s_waitcnt lgkmcnt(0)" ::: "memory"); \
    __builtin_amdgcn_s_barrier(); \
} while (0)

static __device__ __forceinline__ unsigned short f2bf(float f) {
    unsigned int u = __float_as_uint(f);
    u = (u + 0x7fffu + ((u >> 16) & 1u)) >> 16;
    return (unsigned short)u;
}
static __device__ __forceinline__ unsigned int cvt_pk_bf2(float lo, float hi) {
    unsigned int r;
    asm("v_cvt_pk_bf16_f32 %0, %1, %2" : "=v"(r) : "v"(lo), "v"(hi));
    return r;
}
// swizzled byte offset — used IDENTICALLY on write and read sides
static __device__ __forceinline__ int swz128(int r, int c) { return (r * 128 + c) ^ ((r & 7) << 4); }

// ---- fused prologue: x->bf16 convert + both weight transposes ----
__global__ __launch_bounds__(256)
void prologue_kernel(const float* __restrict__ x, unsigned short* __restrict__ xb,
                     const float* __restrict__ w_attn, unsigned short* __restrict__ wTa,
                     const float* __restrict__ w_proj, unsigned short* __restrict__ wTp) {
    __shared__ float tile[32][33];
    const int bid = blockIdx.x, tid = threadIdx.x;
    if (bid < 2048) {
        const int n = 8192 * 768;
        int i = (bid * 256 + tid) * 4;
        const int stride = 2048 * 256 * 4;
        for (; i < n; i += stride) {
            float4 v = *(const float4*)(x + i);
            ushort4 o;
            o.x = f2bf(v.x); o.y = f2bf(v.y); o.z = f2bf(v.z); o.w = f2bf(v.w);
            *(ushort4*)(xb + i) = o;
        }
    } else {
        const float* w; unsigned short* wt; int K, N, bx, by;
        if (bid < 3776) {
            int id = bid - 2048; w = w_attn; wt = wTa; K = 768; N = 2304;
            bx = id % 72; by = id / 72;
        } else {
            int id = bid - 3776; w = w_proj; wt = wTp; K = 768; N = 768;
            bx = id % 24; by = id / 24;
        }
        const int tx = tid & 31, ty = tid >> 5;
        const int n0 = bx * 32, k0 = by * 32;
#pragma unroll
        for (int r = 0; r < 4; r++)
            tile[ty * 4 + r][tx] = w[(size_t)(k0 + ty * 4 + r) * N + n0 + tx];
        __syncthreads();
#pragma unroll
        for (int r = 0; r < 4; r++)
            wt[(size_t)(n0 + ty * 4 + r) * K + k0 + tx] = f2bf(tile[tx][ty * 4 + r]);
    }
}

// ---- GEMM: C[M,N] = A[M,K] * Bt[N,K]^T + bias ----
// 1-D grid, XCD-clustered: xcd=bid&7 owns 8 contiguous m-panels x all n;
// n-fastest order so blocks sharing an A-panel run together (L2-resident).
// 128x128 tile, BK=64, 2-phase dbuf gload_lds staging, counted vmcnt.
template <bool OUT_BF16>
__global__ __launch_bounds__(256, 2)
void gemm_bt(const unsigned short* __restrict__ A, const unsigned short* __restrict__ Bt,
             const float* __restrict__ bias, void* __restrict__ Cout,
             unsigned short* __restrict__ Vt,
             int M, int N, int K, int ldc, int qcols, float qscale) {
    __shared__ char smem[65536];
    const int tid = threadIdx.x, wid = tid >> 6, lane = tid & 63;
    const int g = lane >> 4, lr = lane & 15;
    // XCD-clustered decode (grid = (M/128)*(N/128), multiple of 8)
    const int nx = N >> 7;
    const int ypx = (M >> 7) >> 3;           // m-panels per XCD
    const int xcd = blockIdx.x & 7, ii = blockIdx.x >> 3;
    const int m0 = (xcd * ypx + ii / nx) * 128;
    const int n0 = (ii % nx) * 128;
    const int wm = wid >> 1, wn = wid & 1;

    f32x4 acc[4][4];
#pragma unroll
    for (int i = 0; i < 4; i++)
#pragma unroll
        for (int j = 0; j < 4; j++) acc[i][j] = f32x4{0.f, 0.f, 0.f, 0.f};

    const int rbase = lane >> 3;
    const int cSw = ((lane & 7) << 4) ^ (rbase << 4);

    auto STAGE = [&](int buf, int kt) {
        char* base = smem + buf * 32768;
#pragma unroll
        for (int ww = 0; ww < 4; ww++) {
            int w = wid * 4 + ww;
            int r = w * 8 + rbase;
            const unsigned short* srcA = A + (size_t)(m0 + r) * K + kt + (cSw >> 1);
            __builtin_amdgcn_global_load_lds(AS_G(srcA), AS_L(base + w * 1024), 16, 0, 0);
            const unsigned short* srcB = Bt + (size_t)(n0 + r) * K + kt + (cSw >> 1);
            __builtin_amdgcn_global_load_lds(AS_G(srcB), AS_L(base + 16384 + w * 1024), 16, 0, 0);
        }
    };

    const int nk = K >> 6;
    STAGE(0, 0);

    for (int t = 0; t < nk; t++) {
        if (t + 1 < nk) {
            STAGE((t + 1) & 1, (t + 1) << 6);
            asm volatile("s_waitcnt vmcnt(8)" ::: "memory");
        } else {
            asm volatile("s_waitcnt vmcnt(0)" ::: "memory");
        }
        __builtin_amdgcn_s_barrier();
        char* cbase = smem + (t & 1) * 32768;
#pragma unroll
        for (int ks = 0; ks < 2; ks++) {
            s16x8 af[4], bfr[4];
#pragma unroll
            for (int i = 0; i < 4; i++)
                af[i] = *(const s16x8*)(cbase + swz128(wm * 64 + i * 16 + lr, ks * 64 + g * 16));
#pragma unroll
            for (int j = 0; j < 4; j++)
                bfr[j] = *(const s16x8*)(cbase + 16384 + swz128(wn * 64 + j * 16 + lr, ks * 64 + g * 16));
#pragma unroll
            for (int i = 0; i < 4; i++)
#pragma unroll
                for (int j = 0; j < 4; j++)
                    acc[i][j] = MFMA16x16x32(af[i], bfr[j], acc[i][j]);
        }
        BARRIER_LGKM();
    }

#pragma unroll
    for (int j = 0; j < 4; j++) {
        int c = n0 + wn * 64 + j * 16 + lr;
        float bv = bias[c];
        float cscale = (c < qcols) ? qscale : 1.0f;
        if (Vt != nullptr && c >= 1536) {
            int h = (c - 1536) >> 6, d = (c - 1536) & 63;
#pragma unroll
            for (int i = 0; i < 4; i++) {
                int r0 = m0 + wm * 64 + i * 16 + g * 4;
                int bb = r0 >> 11, t0 = r0 & 2047;
                ushort4 o4;
                o4.x = f2bf(acc[i][j][0] + bv);
                o4.y = f2bf(acc[i][j][1] + bv);
                o4.z = f2bf(acc[i][j][2] + bv);
                o4.w = f2bf(acc[i][j][3] + bv);
                *(ushort4*)(Vt + ((((size_t)bb * 12 + h) * 64 + d) << 11) + t0) = o4;
            }
        } else {
#pragma unroll
            for (int i = 0; i < 4; i++) {
#pragma unroll
                for (int rg = 0; rg < 4; rg++) {
                    int r = m0 + wm * 64 + i * 16 + g * 4 + rg;
                    float val = (acc[i][j][rg] + bv) * cscale;
                    if constexpr (OUT_BF16)
                        ((unsigned short*)Cout)[(size_t)r * ldc + c] = f2bf(val);
                    else
                        ((float*)Cout)[(size_t)r * ldc + c] = val;
                }
            }
        }
    }
}

// ---- causal flash attention: swapped QK^T, merged pair with SHARED K/V
// fragment reads (each ak/bv read once, feeds both q-tiles' MFMAs), dbuf K/V,
// ones-MFMA row-sum, dual P buffers ----
// Grid 768: s -> xcd=s&7, i=s>>3, grp=xcd*6+(i>>4), qpi=i&15 (XCD-clustered).
// LDS 48KB: Kbuf[2] 2x8K | Vbuf[2] 2x8K @+16K | P_B 8K @+32K | P_A 8K @+40K.
__global__ __launch_bounds__(256, 2)
void attn_kernel(const unsigned short* __restrict__ qk, const unsigned short* __restrict__ Vt,
                 unsigned short* __restrict__ y) {
    __shared__ char smem[49152];
    const int tid = threadIdx.x, wid = tid >> 6, lane = tid & 63;
    const int g = lane >> 4, lr = lane & 15;
    const int T = 2048;

    const int s = blockIdx.x;
    const int xcd = s & 7, i = s >> 3;
    const int grp = xcd * 6 + (i >> 4);
    const int qpi = i & 15;
    const int h = grp % 12, b = grp / 12;
    const int qtA = qpi, qtB = 31 - qpi;
    const int q0A = qtA * 64, q0B = qtB * 64;

    const int krow = tid >> 2;
    const int kcol = (tid & 3) * 32;

    s16x8 vone;
#pragma unroll
    for (int e = 0; e < 8; e++) vone[e] = (short)0x3F80;   // bf16 1.0

    const unsigned short* qrowA = qk + (size_t)(b * T + q0A + wid * 16 + lr) * 1536 + h * 64;
    const unsigned short* qrowB = qk + (size_t)(b * T + q0B + wid * 16 + lr) * 1536 + h * 64;
    s16x8 aqA[2], aqB[2];
    aqA[0] = *(const s16x8*)(qrowA + g * 8);
    aqA[1] = *(const s16x8*)(qrowA + 32 + g * 8);
    aqB[0] = *(const s16x8*)(qrowB + g * 8);
    aqB[1] = *(const s16x8*)(qrowB + 32 + g * 8);

    f32x4 oA[4], oB[4], lsumA, lsumB;
#pragma unroll
    for (int r = 0; r < 4; r++) { oA[r] = f32x4{0.f, 0.f, 0.f, 0.f}; oB[r] = f32x4{0.f, 0.f, 0.f, 0.f}; }
    lsumA = f32x4{0.f, 0.f, 0.f, 0.f};
    lsumB = f32x4{0.f, 0.f, 0.f, 0.f};

    const unsigned short* pkBase = qk + (size_t)(b * T + krow) * 1536 + 768 + h * 64 + (kcol >> 1);
    const unsigned short* pvBase = Vt + ((((size_t)b * 12 + h) * 64 + krow) << 11) + (kcol >> 1);

    const int ntA = qtA + 1, ntB = qtB + 1;

    // prologue: load tile 0 -> buf0; issue loads for tile 1
    s16x8 k0 = *(const s16x8*)(pkBase);
    s16x8 k1 = *(const s16x8*)(pkBase + 8);
    s16x8 v0 = *(const s16x8*)(pvBase);
    s16x8 v1 = *(const s16x8*)(pvBase + 8);
    *(s16x8*)(smem + swz128(krow, kcol)) = k0;
    *(s16x8*)(smem + swz128(krow, kcol + 16)) = k1;
    *(s16x8*)(smem + 16384 + swz128(krow, kcol)) = v0;
    *(s16x8*)(smem + 16384 + swz128(krow, kcol + 16)) = v1;
    if (ntB > 1) {
        const unsigned short* pk = pkBase + (size_t)64 * 1536;
        k0 = *(const s16x8*)(pk);
        k1 = *(const s16x8*)(pk + 8);
        const unsigned short* pv = pvBase + 64;
        v0 = *(const s16x8*)(pv);
        v1 = *(const s16x8*)(pv + 8);
    }
    BARRIER_LGKM();

    char* const pbaseB = smem + 32768 + wid * 2048;
    char* const pbaseA = smem + 40960 + wid * 2048;
    const int q_rel = wid * 16 + lr;

    for (int t = 0; t < ntB; t++) {
        char* kbase = smem + (t & 1) * 8192;
        char* vbase = smem + 16384 + (t & 1) * 8192;
        const bool actA = (t < ntA);

        // ---- phase 1: QK^T for BOTH q-tiles, sharing each ak read ----
        f32x4 stB[4], stA[4];
        __builtin_amdgcn_s_setprio(1);
#pragma unroll
        for (int nf = 0; nf < 4; nf++) {
            f32x4 sB = f32x4{0.f, 0.f, 0.f, 0.f};
            f32x4 sA = f32x4{0.f, 0.f, 0.f, 0.f};
#pragma unroll
            for (int ks = 0; ks < 2; ks++) {
                s16x8 ak = *(const s16x8*)(kbase + swz128(nf * 16 + lr, (ks * 32 + g * 8) * 2));
                sB = MFMA16x16x32(ak, aqB[ks], sB);
                if (actA) sA = MFMA16x16x32(ak, aqA[ks], sA);
            }
            stB[nf] = sB;
            stA[nf] = sA;
        }
        __builtin_amdgcn_s_setprio(0);

        // ---- exp + mask + P-write for B ----
        {
            const bool diag = (t == ntB - 1);
#pragma unroll
            for (int nf = 0; nf < 4; nf++)
#pragma unroll
                for (int rg = 0; rg < 4; rg++) {
                    float p = __builtin_amdgcn_exp2f(stB[nf][rg]);
                    if (diag && (nf * 16 + g * 4 + rg > q_rel)) p = 0.f;
                    stB[nf][rg] = p;
                }
#pragma unroll
            for (int nf = 0; nf < 4; nf++) {
                uint2 dw;
                dw.x = cvt_pk_bf2(stB[nf][0], stB[nf][1]);
                dw.y = cvt_pk_bf2(stB[nf][2], stB[nf][3]);
                *(uint2*)(pbaseB + swz128(lr, nf * 32 + g * 8)) = dw;
            }
        }
        // ---- exp + mask + P-write for A ----
        if (actA) {
            const bool diag = (t == ntA - 1);
#pragma unroll
            for (int nf = 0; nf < 4; nf++)
#pragma unroll
                for (int rg = 0; rg < 4; rg++) {
                    float p = __builtin_amdgcn_exp2f(stA[nf][rg]);
                    if (diag && (nf * 16 + g * 4 + rg > q_rel)) p = 0.f;
                    stA[nf][rg] = p;
                }
#pragma unroll
            for (int nf = 0; nf < 4; nf++) {
                uint2 dw;
                dw.x = cvt_pk_bf2(stA[nf][0], stA[nf][1]);
                dw.y = cvt_pk_bf2(stA[nf][2], stA[nf][3]);
                *(uint2*)(pbaseA + swz128(lr, nf * 32 + g * 8)) = dw;
            }
        }

        // ---- phase 2: PV for BOTH q-tiles, sharing each bv read ----
        s16x8 pfB[2], pfA[2];
#pragma unroll
        for (int ks = 0; ks < 2; ks++)
            pfB[ks] = *(const s16x8*)(pbaseB + swz128(lr, ks * 64 + g * 16));
        if (actA) {
#pragma unroll
            for (int ks = 0; ks < 2; ks++)
                pfA[ks] = *(const s16x8*)(pbaseA + swz128(lr, ks * 64 + g * 16));
        }
        __builtin_amdgcn_s_setprio(1);
#pragma unroll
        for (int nf = 0; nf < 4; nf++) {
#pragma unroll
            for (int ks = 0; ks < 2; ks++) {
                s16x8 bv = *(const s16x8*)(vbase + swz128(nf * 16 + lr, ks * 64 + g * 16));
                oB[nf] = MFMA16x16x32(pfB[ks], bv, oB[nf]);
                if (actA) oA[nf] = MFMA16x16x32(pfA[ks], bv, oA[nf]);
            }
        }
        lsumB = MFMA16x16x32(pfB[0], vone, lsumB);
        lsumB = MFMA16x16x32(pfB[1], vone, lsumB);
        if (actA) {
            lsumA = MFMA16x16x32(pfA[0], vone, lsumA);
            lsumA = MFMA16x16x32(pfA[1], vone, lsumA);
        }
        __builtin_amdgcn_s_setprio(0);

        // stage tile t+1 into the other buffer; issue loads for t+2
        if (t + 1 < ntB) {
            char* kn = smem + ((t + 1) & 1) * 8192;
            char* vn = smem + 16384 + ((t + 1) & 1) * 8192;
            *(s16x8*)(kn + swz128(krow, kcol)) = k0;
            *(s16x8*)(kn + swz128(krow, kcol + 16)) = k1;
            *(s16x8*)(vn + swz128(krow, kcol)) = v0;
            *(s16x8*)(vn + swz128(krow, kcol + 16)) = v1;
            if (t + 2 < ntB) {
                const unsigned short* pk = pkBase + (size_t)(t + 2) * 64 * 1536;
                k0 = *(const s16x8*)(pk);
                k1 = *(const s16x8*)(pk + 8);
                const unsigned short* pv = pvBase + (t + 2) * 64;
                v0 = *(const s16x8*)(pv);
                v1 = *(const s16x8*)(pv + 8);
            }
        }
        BARRIER_LGKM();              // single barrier per tile
    }

    // epilogue: lsum[rg] is the row-sum for q = wid*16+g*4+rg — same slot as o
#pragma unroll
    for (int which = 0; which < 2; which++) {
        const f32x4 lsum = which ? lsumB : lsumA;
        const int q0 = which ? q0B : q0A;
        f32x4* o = which ? oB : oA;
        float linv_q[4];
#pragma unroll
        for (int rg = 0; rg < 4; rg++) linv_q[rg] = 1.0f / lsum[rg];
#pragma unroll
        for (int nf = 0; nf < 4; nf++) {
#pragma unroll
            for (int rg = 0; rg < 4; rg++) {
                int row = b * T + q0 + wid * 16 + g * 4 + rg;
                int col = h * 64 + nf * 16 + lr;
                y[(size_t)row * 768 + col] = f2bf(o[nf][rg] * linv_q[rg]);
            }
        }
    }
}

extern "C" void kernel_launch(void* const* d_in, const int* in_sizes, int n_in,
                              void* d_out, int out_size, void* d_ws, size_t ws_size,
                              hipStream_t stream) {
    const float* x      = (const float*)d_in[0];
    const float* w_attn = (const float*)d_in[1];
    const float* b_attn = (const float*)d_in[2];
    const float* w_proj = (const float*)d_in[3];
    const float* b_proj = (const float*)d_in[4];

    char* ws = (char*)d_ws;
    unsigned short* qk  = (unsigned short*)(ws);
    unsigned short* Vt  = (unsigned short*)(ws + 25165824);
    unsigned short* wTa = (unsigned short*)(ws + 37748736);
    unsigned short* wTp = (unsigned short*)(ws + 41287680);

    const bool big = ws_size >= (size_t)55050240;
    unsigned short* xb = (unsigned short*)d_out;
    unsigned short* yb = big ? (unsigned short*)(ws + 42467328)
                             : (unsigned short*)((char*)d_out + 12582912);
    float* projOut = big ? (float*)d_out : (float*)ws;

    prologue_kernel<<<4352, 256, 0, stream>>>(x, xb, w_attn, wTa, w_proj, wTp);

    // qscale = 0.125 * log2(e): softmax scale and exp->exp2 folded into Q
    gemm_bt<true><<<1152, 256, 0, stream>>>(xb, wTa, b_attn, (void*)qk, Vt,
                                            8192, 2304, 768, 1536, 768, 0.1803368801111244f);
    attn_kernel<<<768, 256, 0, stream>>>(qk, Vt, yb);
    gemm_bt<false><<<384, 256, 0, stream>>>(yb, wTp, b_proj, (void*)projOut, nullptr,
                                            8192, 768, 768, 768, 0, 1.0f);
    if (!big)
        hipMemcpyAsync(d_out, projOut, 25165824, hipMemcpyDeviceToDevice, stream);
}

// Round 16
// 123.994 us; speedup vs baseline: 1.0167x; 1.0167x over previous
//
#include <hip/hip_runtime.h>
#include <hip/hip_bf16.h>

using f32x4 = __attribute__((ext_vector_type(4))) float;
using s16x8 = __attribute__((ext_vector_type(8))) short;

#define MFMA16x16x32(a, b, c) __builtin_amdgcn_mfma_f32_16x16x32_bf16((a), (b), (c), 0, 0, 0)

#define AS_G(p) ((const __attribute__((address_space(1))) void*)(p))
#define AS_L(p) ((__attribute__((address_space(3))) void*)(p))

// barrier with LDS-visibility only: does NOT drain vmcnt
#define BARRIER_LGKM() do { \
    asm volatile("s_waitcnt lgkmcnt(0)" ::: "memory"); \
    __builtin_amdgcn_s_barrier(); \
} while (0)

static __device__ __forceinline__ unsigned short f2bf(float f) {
    unsigned int u = __float_as_uint(f);
    u = (u + 0x7fffu + ((u >> 16) & 1u)) >> 16;
    return (unsigned short)u;
}
static __device__ __forceinline__ unsigned int cvt_pk_bf2(float lo, float hi) {
    unsigned int r;
    asm("v_cvt_pk_bf16_f32 %0, %1, %2" : "=v"(r) : "v"(lo), "v"(hi));
    return r;
}
// swizzled byte offset — used IDENTICALLY on write and read sides
static __device__ __forceinline__ int swz128(int r, int c) { return (r * 128 + c) ^ ((r & 7) << 4); }

// ---- fused prologue: x->bf16 convert + both weight transposes ----
__global__ __launch_bounds__(256)
void prologue_kernel(const float* __restrict__ x, unsigned short* __restrict__ xb,
                     const float* __restrict__ w_attn, unsigned short* __restrict__ wTa,
                     const float* __restrict__ w_proj, unsigned short* __restrict__ wTp) {
    __shared__ float tile[32][33];
    const int bid = blockIdx.x, tid = threadIdx.x;
    if (bid < 2048) {
        const int n = 8192 * 768;
        int i = (bid * 256 + tid) * 4;
        const int stride = 2048 * 256 * 4;
        for (; i < n; i += stride) {
            float4 v = *(const float4*)(x + i);
            ushort4 o;
            o.x = f2bf(v.x); o.y = f2bf(v.y); o.z = f2bf(v.z); o.w = f2bf(v.w);
            *(ushort4*)(xb + i) = o;
        }
    } else {
        const float* w; unsigned short* wt; int K, N, bx, by;
        if (bid < 3776) {
            int id = bid - 2048; w = w_attn; wt = wTa; K = 768; N = 2304;
            bx = id % 72; by = id / 72;
        } else {
            int id = bid - 3776; w = w_proj; wt = wTp; K = 768; N = 768;
            bx = id % 24; by = id / 24;
        }
        const int tx = tid & 31, ty = tid >> 5;
        const int n0 = bx * 32, k0 = by * 32;
#pragma unroll
        for (int r = 0; r < 4; r++)
            tile[ty * 4 + r][tx] = w[(size_t)(k0 + ty * 4 + r) * N + n0 + tx];
        __syncthreads();
#pragma unroll
        for (int r = 0; r < 4; r++)
            wt[(size_t)(n0 + ty * 4 + r) * K + k0 + tx] = f2bf(tile[tx][ty * 4 + r]);
    }
}

// ---- GEMM: C[M,N] = A[M,K] * Bt[N,K]^T + bias ----
// 1-D grid, XCD-clustered (kept from round 15: non-attn time 74.4 -> 71.9).
template <bool OUT_BF16>
__global__ __launch_bounds__(256, 2)
void gemm_bt(const unsigned short* __restrict__ A, const unsigned short* __restrict__ Bt,
             const float* __restrict__ bias, void* __restrict__ Cout,
             unsigned short* __restrict__ Vt,
             int M, int N, int K, int ldc, int qcols, float qscale) {
    __shared__ char smem[65536];
    const int tid = threadIdx.x, wid = tid >> 6, lane = tid & 63;
    const int g = lane >> 4, lr = lane & 15;
    const int nx = N >> 7;
    const int ypx = (M >> 7) >> 3;
    const int xcd = blockIdx.x & 7, ii = blockIdx.x >> 3;
    const int m0 = (xcd * ypx + ii / nx) * 128;
    const int n0 = (ii % nx) * 128;
    const int wm = wid >> 1, wn = wid & 1;

    f32x4 acc[4][4];
#pragma unroll
    for (int i = 0; i < 4; i++)
#pragma unroll
        for (int j = 0; j < 4; j++) acc[i][j] = f32x4{0.f, 0.f, 0.f, 0.f};

    const int rbase = lane >> 3;
    const int cSw = ((lane & 7) << 4) ^ (rbase << 4);

    auto STAGE = [&](int buf, int kt) {
        char* base = smem + buf * 32768;
#pragma unroll
        for (int ww = 0; ww < 4; ww++) {
            int w = wid * 4 + ww;
            int r = w * 8 + rbase;
            const unsigned short* srcA = A + (size_t)(m0 + r) * K + kt + (cSw >> 1);
            __builtin_amdgcn_global_load_lds(AS_G(srcA), AS_L(base + w * 1024), 16, 0, 0);
            const unsigned short* srcB = Bt + (size_t)(n0 + r) * K + kt + (cSw >> 1);
            __builtin_amdgcn_global_load_lds(AS_G(srcB), AS_L(base + 16384 + w * 1024), 16, 0, 0);
        }
    };

    const int nk = K >> 6;
    STAGE(0, 0);

    for (int t = 0; t < nk; t++) {
        if (t + 1 < nk) {
            STAGE((t + 1) & 1, (t + 1) << 6);
            asm volatile("s_waitcnt vmcnt(8)" ::: "memory");
        } else {
            asm volatile("s_waitcnt vmcnt(0)" ::: "memory");
        }
        __builtin_amdgcn_s_barrier();
        char* cbase = smem + (t & 1) * 32768;
#pragma unroll
        for (int ks = 0; ks < 2; ks++) {
            s16x8 af[4], bfr[4];
#pragma unroll
            for (int i = 0; i < 4; i++)
                af[i] = *(const s16x8*)(cbase + swz128(wm * 64 + i * 16 + lr, ks * 64 + g * 16));
#pragma unroll
            for (int j = 0; j < 4; j++)
                bfr[j] = *(const s16x8*)(cbase + 16384 + swz128(wn * 64 + j * 16 + lr, ks * 64 + g * 16));
#pragma unroll
            for (int i = 0; i < 4; i++)
#pragma unroll
                for (int j = 0; j < 4; j++)
                    acc[i][j] = MFMA16x16x32(af[i], bfr[j], acc[i][j]);
        }
        BARRIER_LGKM();
    }

#pragma unroll
    for (int j = 0; j < 4; j++) {
        int c = n0 + wn * 64 + j * 16 + lr;
        float bv = bias[c];
        float cscale = (c < qcols) ? qscale : 1.0f;
        if (Vt != nullptr && c >= 1536) {
            int h = (c - 1536) >> 6, d = (c - 1536) & 63;
#pragma unroll
            for (int i = 0; i < 4; i++) {
                int r0 = m0 + wm * 64 + i * 16 + g * 4;
                int bb = r0 >> 11, t0 = r0 & 2047;
                ushort4 o4;
                o4.x = f2bf(acc[i][j][0] + bv);
                o4.y = f2bf(acc[i][j][1] + bv);
                o4.z = f2bf(acc[i][j][2] + bv);
                o4.w = f2bf(acc[i][j][3] + bv);
                *(ushort4*)(Vt + ((((size_t)bb * 12 + h) * 64 + d) << 11) + t0) = o4;
            }
        } else {
#pragma unroll
            for (int i = 0; i < 4; i++) {
#pragma unroll
                for (int rg = 0; rg < 4; rg++) {
                    int r = m0 + wm * 64 + i * 16 + g * 4 + rg;
                    float val = (acc[i][j][rg] + bv) * cscale;
                    if constexpr (OUT_BF16)
                        ((unsigned short*)Cout)[(size_t)r * ldc + c] = f2bf(val);
                    else
                        ((float*)Cout)[(size_t)r * ldc + c] = val;
                }
            }
        }
    }
}

// ---- causal flash attention: swapped QK^T, merged pair, dbuf K/V,
// ones-MFMA row-sum, dual P buffers. Shared K/V fragment reads with the
// wave-uniform actA branch HOISTED out of the MFMA loops (round-15 lesson:
// per-unroll-instance predication fragments the MFMA clusters). ----
__global__ __launch_bounds__(256, 2)
void attn_kernel(const unsigned short* __restrict__ qk, const unsigned short* __restrict__ Vt,
                 unsigned short* __restrict__ y) {
    __shared__ char smem[49152];
    const int tid = threadIdx.x, wid = tid >> 6, lane = tid & 63;
    const int g = lane >> 4, lr = lane & 15;
    const int T = 2048;

    const int s = blockIdx.x;
    const int xcd = s & 7, i = s >> 3;
    const int grp = xcd * 6 + (i >> 4);
    const int qpi = i & 15;
    const int h = grp % 12, b = grp / 12;
    const int qtA = qpi, qtB = 31 - qpi;
    const int q0A = qtA * 64, q0B = qtB * 64;

    const int krow = tid >> 2;
    const int kcol = (tid & 3) * 32;

    s16x8 vone;
#pragma unroll
    for (int e = 0; e < 8; e++) vone[e] = (short)0x3F80;   // bf16 1.0

    const unsigned short* qrowA = qk + (size_t)(b * T + q0A + wid * 16 + lr) * 1536 + h * 64;
    const unsigned short* qrowB = qk + (size_t)(b * T + q0B + wid * 16 + lr) * 1536 + h * 64;
    s16x8 aqA[2], aqB[2];
    aqA[0] = *(const s16x8*)(qrowA + g * 8);
    aqA[1] = *(const s16x8*)(qrowA + 32 + g * 8);
    aqB[0] = *(const s16x8*)(qrowB + g * 8);
    aqB[1] = *(const s16x8*)(qrowB + 32 + g * 8);

    f32x4 oA[4], oB[4], lsumA, lsumB;
#pragma unroll
    for (int r = 0; r < 4; r++) { oA[r] = f32x4{0.f, 0.f, 0.f, 0.f}; oB[r] = f32x4{0.f, 0.f, 0.f, 0.f}; }
    lsumA = f32x4{0.f, 0.f, 0.f, 0.f};
    lsumB = f32x4{0.f, 0.f, 0.f, 0.f};

    const unsigned short* pkBase = qk + (size_t)(b * T + krow) * 1536 + 768 + h * 64 + (kcol >> 1);
    const unsigned short* pvBase = Vt + ((((size_t)b * 12 + h) * 64 + krow) << 11) + (kcol >> 1);

    const int ntA = qtA + 1, ntB = qtB + 1;

    // prologue: load tile 0 -> buf0; issue loads for tile 1
    s16x8 k0 = *(const s16x8*)(pkBase);
    s16x8 k1 = *(const s16x8*)(pkBase + 8);
    s16x8 v0 = *(const s16x8*)(pvBase);
    s16x8 v1 = *(const s16x8*)(pvBase + 8);
    *(s16x8*)(smem + swz128(krow, kcol)) = k0;
    *(s16x8*)(smem + swz128(krow, kcol + 16)) = k1;
    *(s16x8*)(smem + 16384 + swz128(krow, kcol)) = v0;
    *(s16x8*)(smem + 16384 + swz128(krow, kcol + 16)) = v1;
    if (ntB > 1) {
        const unsigned short* pk = pkBase + (size_t)64 * 1536;
        k0 = *(const s16x8*)(pk);
        k1 = *(const s16x8*)(pk + 8);
        const unsigned short* pv = pvBase + 64;
        v0 = *(const s16x8*)(pv);
        v1 = *(const s16x8*)(pv + 8);
    }
    BARRIER_LGKM();

    char* const pbaseB = smem + 32768 + wid * 2048;
    char* const pbaseA = smem + 40960 + wid * 2048;
    const int q_rel = wid * 16 + lr;

    for (int t = 0; t < ntB; t++) {
        char* kbase = smem + (t & 1) * 8192;
        char* vbase = smem + 16384 + (t & 1) * 8192;

        if (t < ntA) {
            // ======== MERGED body: branch-free, shared ak/bv reads ========
            f32x4 stB[4], stA[4];
            __builtin_amdgcn_s_setprio(1);
#pragma unroll
            for (int nf = 0; nf < 4; nf++) {
                f32x4 sB = f32x4{0.f, 0.f, 0.f, 0.f};
                f32x4 sA = f32x4{0.f, 0.f, 0.f, 0.f};
#pragma unroll
                for (int ks = 0; ks < 2; ks++) {
                    s16x8 ak = *(const s16x8*)(kbase + swz128(nf * 16 + lr, (ks * 32 + g * 8) * 2));
                    sB = MFMA16x16x32(ak, aqB[ks], sB);
                    sA = MFMA16x16x32(ak, aqA[ks], sA);
                }
                stB[nf] = sB;
                stA[nf] = sA;
            }
            __builtin_amdgcn_s_setprio(0);

            {
                const bool diagB = (t == ntB - 1);
#pragma unroll
                for (int nf = 0; nf < 4; nf++)
#pragma unroll
                    for (int rg = 0; rg < 4; rg++) {
                        float p = __builtin_amdgcn_exp2f(stB[nf][rg]);
                        if (diagB && (nf * 16 + g * 4 + rg > q_rel)) p = 0.f;
                        stB[nf][rg] = p;
                    }
#pragma unroll
                for (int nf = 0; nf < 4; nf++) {
                    uint2 dw;
                    dw.x = cvt_pk_bf2(stB[nf][0], stB[nf][1]);
                    dw.y = cvt_pk_bf2(stB[nf][2], stB[nf][3]);
                    *(uint2*)(pbaseB + swz128(lr, nf * 32 + g * 8)) = dw;
                }
                const bool diagA = (t == ntA - 1);
#pragma unroll
                for (int nf = 0; nf < 4; nf++)
#pragma unroll
                    for (int rg = 0; rg < 4; rg++) {
                        float p = __builtin_amdgcn_exp2f(stA[nf][rg]);
                        if (diagA && (nf * 16 + g * 4 + rg > q_rel)) p = 0.f;
                        stA[nf][rg] = p;
                    }
#pragma unroll
                for (int nf = 0; nf < 4; nf++) {
                    uint2 dw;
                    dw.x = cvt_pk_bf2(stA[nf][0], stA[nf][1]);
                    dw.y = cvt_pk_bf2(stA[nf][2], stA[nf][3]);
                    *(uint2*)(pbaseA + swz128(lr, nf * 32 + g * 8)) = dw;
                }
            }

            s16x8 pfB[2], pfA[2];
#pragma unroll
            for (int ks = 0; ks < 2; ks++) {
                pfB[ks] = *(const s16x8*)(pbaseB + swz128(lr, ks * 64 + g * 16));
                pfA[ks] = *(const s16x8*)(pbaseA + swz128(lr, ks * 64 + g * 16));
            }
            __builtin_amdgcn_s_setprio(1);
#pragma unroll
            for (int nf = 0; nf < 4; nf++) {
#pragma unroll
                for (int ks = 0; ks < 2; ks++) {
                    s16x8 bv = *(const s16x8*)(vbase + swz128(nf * 16 + lr, ks * 64 + g * 16));
                    oB[nf] = MFMA16x16x32(pfB[ks], bv, oB[nf]);
                    oA[nf] = MFMA16x16x32(pfA[ks], bv, oA[nf]);
                }
            }
            lsumB = MFMA16x16x32(pfB[0], vone, lsumB);
            lsumB = MFMA16x16x32(pfB[1], vone, lsumB);
            lsumA = MFMA16x16x32(pfA[0], vone, lsumA);
            lsumA = MFMA16x16x32(pfA[1], vone, lsumA);
            __builtin_amdgcn_s_setprio(0);
        } else {
            // ======== B-only body (identical to round-14 structure) ========
            f32x4 stB[4];
            __builtin_amdgcn_s_setprio(1);
#pragma unroll
            for (int nf = 0; nf < 4; nf++) {
                f32x4 sB = f32x4{0.f, 0.f, 0.f, 0.f};
#pragma unroll
                for (int ks = 0; ks < 2; ks++) {
                    s16x8 ak = *(const s16x8*)(kbase + swz128(nf * 16 + lr, (ks * 32 + g * 8) * 2));
                    sB = MFMA16x16x32(ak, aqB[ks], sB);
                }
                stB[nf] = sB;
            }
            __builtin_amdgcn_s_setprio(0);

            const bool diagB = (t == ntB - 1);
#pragma unroll
            for (int nf = 0; nf < 4; nf++)
#pragma unroll
                for (int rg = 0; rg < 4; rg++) {
                    float p = __builtin_amdgcn_exp2f(stB[nf][rg]);
                    if (diagB && (nf * 16 + g * 4 + rg > q_rel)) p = 0.f;
                    stB[nf][rg] = p;
                }
#pragma unroll
            for (int nf = 0; nf < 4; nf++) {
                uint2 dw;
                dw.x = cvt_pk_bf2(stB[nf][0], stB[nf][1]);
                dw.y = cvt_pk_bf2(stB[nf][2], stB[nf][3]);
                *(uint2*)(pbaseB + swz128(lr, nf * 32 + g * 8)) = dw;
            }

            s16x8 pfB[2];
#pragma unroll
            for (int ks = 0; ks < 2; ks++)
                pfB[ks] = *(const s16x8*)(pbaseB + swz128(lr, ks * 64 + g * 16));
            __builtin_amdgcn_s_setprio(1);
#pragma unroll
            for (int nf = 0; nf < 4; nf++) {
#pragma unroll
                for (int ks = 0; ks < 2; ks++) {
                    s16x8 bv = *(const s16x8*)(vbase + swz128(nf * 16 + lr, ks * 64 + g * 16));
                    oB[nf] = MFMA16x16x32(pfB[ks], bv, oB[nf]);
                }
            }
            lsumB = MFMA16x16x32(pfB[0], vone, lsumB);
            lsumB = MFMA16x16x32(pfB[1], vone, lsumB);
            __builtin_amdgcn_s_setprio(0);
        }

        // stage tile t+1 into the other buffer; issue loads for t+2
        if (t + 1 < ntB) {
            char* kn = smem + ((t + 1) & 1) * 8192;
            char* vn = smem + 16384 + ((t + 1) & 1) * 8192;
            *(s16x8*)(kn + swz128(krow, kcol)) = k0;
            *(s16x8*)(kn + swz128(krow, kcol + 16)) = k1;
            *(s16x8*)(vn + swz128(krow, kcol)) = v0;
            *(s16x8*)(vn + swz128(krow, kcol + 16)) = v1;
            if (t + 2 < ntB) {
                const unsigned short* pk = pkBase + (size_t)(t + 2) * 64 * 1536;
                k0 = *(const s16x8*)(pk);
                k1 = *(const s16x8*)(pk + 8);
                const unsigned short* pv = pvBase + (t + 2) * 64;
                v0 = *(const s16x8*)(pv);
                v1 = *(const s16x8*)(pv + 8);
            }
        }
        BARRIER_LGKM();              // single barrier per tile
    }

    // epilogue: lsum[rg] is the row-sum for q = wid*16+g*4+rg — same slot as o
#pragma unroll
    for (int which = 0; which < 2; which++) {
        const f32x4 lsum = which ? lsumB : lsumA;
        const int q0 = which ? q0B : q0A;
        f32x4* o = which ? oB : oA;
        float linv_q[4];
#pragma unroll
        for (int rg = 0; rg < 4; rg++) linv_q[rg] = 1.0f / lsum[rg];
#pragma unroll
        for (int nf = 0; nf < 4; nf++) {
#pragma unroll
            for (int rg = 0; rg < 4; rg++) {
                int row = b * T + q0 + wid * 16 + g * 4 + rg;
                int col = h * 64 + nf * 16 + lr;
                y[(size_t)row * 768 + col] = f2bf(o[nf][rg] * linv_q[rg]);
            }
        }
    }
}

extern "C" void kernel_launch(void* const* d_in, const int* in_sizes, int n_in,
                              void* d_out, int out_size, void* d_ws, size_t ws_size,
                              hipStream_t stream) {
    const float* x      = (const float*)d_in[0];
    const float* w_attn = (const float*)d_in[1];
    const float* b_attn = (const float*)d_in[2];
    const float* w_proj = (const float*)d_in[3];
    const float* b_proj = (const float*)d_in[4];

    char* ws = (char*)d_ws;
    unsigned short* qk  = (unsigned short*)(ws);
    unsigned short* Vt  = (unsigned short*)(ws + 25165824);
    unsigned short* wTa = (unsigned short*)(ws + 37748736);
    unsigned short* wTp = (unsigned short*)(ws + 41287680);

    const bool big = ws_size >= (size_t)55050240;
    unsigned short* xb = (unsigned short*)d_out;
    unsigned short* yb = big ? (unsigned short*)(ws + 42467328)
                             : (unsigned short*)((char*)d_out + 12582912);
    float* projOut = big ? (float*)d_out : (float*)ws;

    prologue_kernel<<<4352, 256, 0, stream>>>(x, xb, w_attn, wTa, w_proj, wTp);

    // qscale = 0.125 * log2(e): softmax scale and exp->exp2 folded into Q
    gemm_bt<true><<<1152, 256, 0, stream>>>(xb, wTa, b_attn, (void*)qk, Vt,
                                            8192, 2304, 768, 1536, 768, 0.1803368801111244f);
    attn_kernel<<<768, 256, 0, stream>>>(qk, Vt, yb);
    gemm_bt<false><<<384, 256, 0, stream>>>(yb, wTp, b_proj, (void*)projOut, nullptr,
                                            8192, 768, 768, 768, 0, 1.0f);
    if (!big)
        hipMemcpyAsync(d_out, projOut, 25165824, hipMemcpyDeviceToDevice, stream);
}

// Round 17
// 122.676 us; speedup vs baseline: 1.0276x; 1.0107x over previous
//
#include <hip/hip_runtime.h>
#include <hip/hip_bf16.h>

using f32x4 = __attribute__((ext_vector_type(4))) float;
using s16x8 = __attribute__((ext_vector_type(8))) short;

#define MFMA16x16x32(a, b, c) __builtin_amdgcn_mfma_f32_16x16x32_bf16((a), (b), (c), 0, 0, 0)

#define AS_G(p) ((const __attribute__((address_space(1))) void*)(p))
#define AS_L(p) ((__attribute__((address_space(3))) void*)(p))

// barrier with LDS-visibility only: does NOT drain vmcnt
#define BARRIER_LGKM() do { \
    asm volatile("s_waitcnt lgkmcnt(0)" ::: "memory"); \
    __builtin_amdgcn_s_barrier(); \
} while (0)

static __device__ __forceinline__ unsigned short f2bf(float f) {
    unsigned int u = __float_as_uint(f);
    u = (u + 0x7fffu + ((u >> 16) & 1u)) >> 16;
    return (unsigned short)u;
}
static __device__ __forceinline__ unsigned int cvt_pk_bf2(float lo, float hi) {
    unsigned int r;
    asm("v_cvt_pk_bf16_f32 %0, %1, %2" : "=v"(r) : "v"(lo), "v"(hi));
    return r;
}
// swizzled byte offset — used IDENTICALLY on write and read sides
static __device__ __forceinline__ int swz128(int r, int c) { return (r * 128 + c) ^ ((r & 7) << 4); }

// ---- fused prologue: x->bf16 convert + both weight transposes ----
__global__ __launch_bounds__(256)
void prologue_kernel(const float* __restrict__ x, unsigned short* __restrict__ xb,
                     const float* __restrict__ w_attn, unsigned short* __restrict__ wTa,
                     const float* __restrict__ w_proj, unsigned short* __restrict__ wTp) {
    __shared__ float tile[32][33];
    const int bid = blockIdx.x, tid = threadIdx.x;
    if (bid < 2048) {
        const int n = 8192 * 768;
        int i = (bid * 256 + tid) * 4;
        const int stride = 2048 * 256 * 4;
        for (; i < n; i += stride) {
            float4 v = *(const float4*)(x + i);
            ushort4 o;
            o.x = f2bf(v.x); o.y = f2bf(v.y); o.z = f2bf(v.z); o.w = f2bf(v.w);
            *(ushort4*)(xb + i) = o;
        }
    } else {
        const float* w; unsigned short* wt; int K, N, bx, by;
        if (bid < 3776) {
            int id = bid - 2048; w = w_attn; wt = wTa; K = 768; N = 2304;
            bx = id % 72; by = id / 72;
        } else {
            int id = bid - 3776; w = w_proj; wt = wTp; K = 768; N = 768;
            bx = id % 24; by = id / 24;
        }
        const int tx = tid & 31, ty = tid >> 5;
        const int n0 = bx * 32, k0 = by * 32;
#pragma unroll
        for (int r = 0; r < 4; r++)
            tile[ty * 4 + r][tx] = w[(size_t)(k0 + ty * 4 + r) * N + n0 + tx];
        __syncthreads();
#pragma unroll
        for (int r = 0; r < 4; r++)
            wt[(size_t)(n0 + ty * 4 + r) * K + k0 + tx] = f2bf(tile[tx][ty * 4 + r]);
    }
}

// ---- GEMM: C[M,N] = A[M,K] * Bt[N,K]^T + bias ----
// BK=32, 128x128 tile. LDS per buffer: INTERLEAVED [128 rows][A 64B | B 64B]
// = 16KB, double-buffered = 32KB total -> 4-5 blocks/CU (occupancy fix:
// m132 showed 64KB/2-blocks collapses to ~508 TF; m97's 16KB/high-occ = 874).
// 128B rows keep the self-inverse swz128 XOR valid. Staging: gload_lds,
// linear dest = wave-uniform base + lane*16 (proven pattern); per-thread
// source resolves to A or B via the inverse swizzle (r&7 is issue-invariant
// so the swizzled column + matrix select are computed ONCE).
// 1-D grid, XCD-clustered. Counted vmcnt(4): next tile's 4 loads in flight.
template <bool OUT_BF16>
__global__ __launch_bounds__(256, 4)
void gemm_bt(const unsigned short* __restrict__ A, const unsigned short* __restrict__ Bt,
             const float* __restrict__ bias, void* __restrict__ Cout,
             unsigned short* __restrict__ Vt,
             int M, int N, int K, int ldc, int qcols, float qscale) {
    __shared__ char smem[32768];
    const int tid = threadIdx.x, wid = tid >> 6, lane = tid & 63;
    const int g = lane >> 4, lr = lane & 15;
    const int nx = N >> 7;
    const int ypx = (M >> 7) >> 3;
    const int xcd = blockIdx.x & 7, ii = blockIdx.x >> 3;
    const int m0 = (xcd * ypx + ii / nx) * 128;
    const int n0 = (ii % nx) * 128;
    const int wm = wid >> 1, wn = wid & 1;

    f32x4 acc[4][4];
#pragma unroll
    for (int i = 0; i < 4; i++)
#pragma unroll
        for (int j = 0; j < 4; j++) acc[i][j] = f32x4{0.f, 0.f, 0.f, 0.f};

    // staging geometry: issue i covers rows i*32 + rr, dest = i*4K + tid*16.
    // inverse swizzle: c = ((tid&7)<<4) ^ ((rr&7)<<4); c<64 -> A, else B.
    const int rr = tid >> 3;
    const int cS = ((tid & 7) << 4) ^ ((rr & 7) << 4);
    const bool isB = cS >= 64;
    const int colE = (isB ? cS - 64 : cS) >> 1;
    const unsigned short* bp = isB ? (Bt + (size_t)(n0 + rr) * K + colE)
                                   : (A + (size_t)(m0 + rr) * K + colE);

    auto STAGE = [&](int buf, int kt) {
        char* base = smem + buf * 16384 + wid * 1024;
#pragma unroll
        for (int i = 0; i < 4; i++)
            __builtin_amdgcn_global_load_lds(AS_G(bp + (size_t)i * 32 * K + kt),
                                             AS_L(base + i * 4096), 16, 0, 0);
    };

    const int nk = K >> 5;               // BK=32
    STAGE(0, 0);

    for (int t = 0; t < nk; t++) {
        if (t + 1 < nk) {
            STAGE((t + 1) & 1, (t + 1) << 5);
            asm volatile("s_waitcnt vmcnt(4)" ::: "memory");   // t's 4 loads done
        } else {
            asm volatile("s_waitcnt vmcnt(0)" ::: "memory");
        }
        __builtin_amdgcn_s_barrier();
        char* cbase = smem + (t & 1) * 16384;
        s16x8 af[4], bfr[4];
#pragma unroll
        for (int i = 0; i < 4; i++)
            af[i] = *(const s16x8*)(cbase + swz128(wm * 64 + i * 16 + lr, g * 16));
#pragma unroll
        for (int j = 0; j < 4; j++)
            bfr[j] = *(const s16x8*)(cbase + swz128(wn * 64 + j * 16 + lr, 64 + g * 16));
#pragma unroll
        for (int i = 0; i < 4; i++)
#pragma unroll
            for (int j = 0; j < 4; j++)
                acc[i][j] = MFMA16x16x32(af[i], bfr[j], acc[i][j]);
        BARRIER_LGKM();   // readers done before STAGE(t+2) overwrites buf[t&1]
    }

#pragma unroll
    for (int j = 0; j < 4; j++) {
        int c = n0 + wn * 64 + j * 16 + lr;
        float bv = bias[c];
        float cscale = (c < qcols) ? qscale : 1.0f;
        if (Vt != nullptr && c >= 1536) {
            int h = (c - 1536) >> 6, d = (c - 1536) & 63;
#pragma unroll
            for (int i = 0; i < 4; i++) {
                int r0 = m0 + wm * 64 + i * 16 + g * 4;
                int bb = r0 >> 11, t0 = r0 & 2047;
                ushort4 o4;
                o4.x = f2bf(acc[i][j][0] + bv);
                o4.y = f2bf(acc[i][j][1] + bv);
                o4.z = f2bf(acc[i][j][2] + bv);
                o4.w = f2bf(acc[i][j][3] + bv);
                *(ushort4*)(Vt + ((((size_t)bb * 12 + h) * 64 + d) << 11) + t0) = o4;
            }
        } else {
#pragma unroll
            for (int i = 0; i < 4; i++) {
#pragma unroll
                for (int rg = 0; rg < 4; rg++) {
                    int r = m0 + wm * 64 + i * 16 + g * 4 + rg;
                    float val = (acc[i][j][rg] + bv) * cscale;
                    if constexpr (OUT_BF16)
                        ((unsigned short*)Cout)[(size_t)r * ldc + c] = f2bf(val);
                    else
                        ((float*)Cout)[(size_t)r * ldc + c] = val;
                }
            }
        }
    }
}

// ---- causal flash attention: EXACT round-14 body (best: 49.4 us) ----
// swapped QK^T, merged pair, dbuf K/V, ones-MFMA row-sum, dual P buffers,
// software-pipelined A/B phases (separate sequential bodies).
__global__ __launch_bounds__(256, 2)
void attn_kernel(const unsigned short* __restrict__ qk, const unsigned short* __restrict__ Vt,
                 unsigned short* __restrict__ y) {
    __shared__ char smem[49152];
    const int tid = threadIdx.x, wid = tid >> 6, lane = tid & 63;
    const int g = lane >> 4, lr = lane & 15;
    const int T = 2048;

    const int s = blockIdx.x;
    const int xcd = s & 7, i = s >> 3;
    const int grp = xcd * 6 + (i >> 4);
    const int qpi = i & 15;
    const int h = grp % 12, b = grp / 12;
    const int qtA = qpi, qtB = 31 - qpi;
    const int q0A = qtA * 64, q0B = qtB * 64;

    const int krow = tid >> 2;
    const int kcol = (tid & 3) * 32;

    s16x8 vone;
#pragma unroll
    for (int e = 0; e < 8; e++) vone[e] = (short)0x3F80;   // bf16 1.0

    const unsigned short* qrowA = qk + (size_t)(b * T + q0A + wid * 16 + lr) * 1536 + h * 64;
    const unsigned short* qrowB = qk + (size_t)(b * T + q0B + wid * 16 + lr) * 1536 + h * 64;
    s16x8 aqA[2], aqB[2];
    aqA[0] = *(const s16x8*)(qrowA + g * 8);
    aqA[1] = *(const s16x8*)(qrowA + 32 + g * 8);
    aqB[0] = *(const s16x8*)(qrowB + g * 8);
    aqB[1] = *(const s16x8*)(qrowB + 32 + g * 8);

    f32x4 oA[4], oB[4], lsumA, lsumB;
#pragma unroll
    for (int r = 0; r < 4; r++) { oA[r] = f32x4{0.f, 0.f, 0.f, 0.f}; oB[r] = f32x4{0.f, 0.f, 0.f, 0.f}; }
    lsumA = f32x4{0.f, 0.f, 0.f, 0.f};
    lsumB = f32x4{0.f, 0.f, 0.f, 0.f};

    const unsigned short* pkBase = qk + (size_t)(b * T + krow) * 1536 + 768 + h * 64 + (kcol >> 1);
    const unsigned short* pvBase = Vt + ((((size_t)b * 12 + h) * 64 + krow) << 11) + (kcol >> 1);

    const int ntA = qtA + 1, ntB = qtB + 1;

    // prologue: load tile 0 -> buf0; issue loads for tile 1
    s16x8 k0 = *(const s16x8*)(pkBase);
    s16x8 k1 = *(const s16x8*)(pkBase + 8);
    s16x8 v0 = *(const s16x8*)(pvBase);
    s16x8 v1 = *(const s16x8*)(pvBase + 8);
    *(s16x8*)(smem + swz128(krow, kcol)) = k0;
    *(s16x8*)(smem + swz128(krow, kcol + 16)) = k1;
    *(s16x8*)(smem + 16384 + swz128(krow, kcol)) = v0;
    *(s16x8*)(smem + 16384 + swz128(krow, kcol + 16)) = v1;
    if (ntB > 1) {
        const unsigned short* pk = pkBase + (size_t)64 * 1536;
        k0 = *(const s16x8*)(pk);
        k1 = *(const s16x8*)(pk + 8);
        const unsigned short* pv = pvBase + 64;
        v0 = *(const s16x8*)(pv);
        v1 = *(const s16x8*)(pv + 8);
    }
    BARRIER_LGKM();

    char* const pbaseB = smem + 32768 + wid * 2048;
    char* const pbaseA = smem + 40960 + wid * 2048;
    const int q_rel = wid * 16 + lr;

    for (int t = 0; t < ntB; t++) {
        char* kbase = smem + (t & 1) * 8192;
        char* vbase = smem + 16384 + (t & 1) * 8192;
        const bool actA = (t < ntA);

        // ---- phase 1: QK^T + exp + P-write for B, then A (separate buffers) ----
        {
            f32x4 st[4];
            __builtin_amdgcn_s_setprio(1);
#pragma unroll
            for (int nf = 0; nf < 4; nf++) {
                f32x4 sf = f32x4{0.f, 0.f, 0.f, 0.f};
#pragma unroll
                for (int ks = 0; ks < 2; ks++) {
                    s16x8 ak = *(const s16x8*)(kbase + swz128(nf * 16 + lr, (ks * 32 + g * 8) * 2));
                    sf = MFMA16x16x32(ak, aqB[ks], sf);
                }
                st[nf] = sf;
            }
            __builtin_amdgcn_s_setprio(0);
            const bool diag = (t == ntB - 1);
#pragma unroll
            for (int nf = 0; nf < 4; nf++)
#pragma unroll
                for (int rg = 0; rg < 4; rg++) {
                    float p = __builtin_amdgcn_exp2f(st[nf][rg]);
                    if (diag && (nf * 16 + g * 4 + rg > q_rel)) p = 0.f;
                    st[nf][rg] = p;
                }
#pragma unroll
            for (int nf = 0; nf < 4; nf++) {
                uint2 dw;
                dw.x = cvt_pk_bf2(st[nf][0], st[nf][1]);
                dw.y = cvt_pk_bf2(st[nf][2], st[nf][3]);
                *(uint2*)(pbaseB + swz128(lr, nf * 32 + g * 8)) = dw;
            }
        }
        if (actA) {
            f32x4 st[4];
            __builtin_amdgcn_s_setprio(1);
#pragma unroll
            for (int nf = 0; nf < 4; nf++) {
                f32x4 sf = f32x4{0.f, 0.f, 0.f, 0.f};
#pragma unroll
                for (int ks = 0; ks < 2; ks++) {
                    s16x8 ak = *(const s16x8*)(kbase + swz128(nf * 16 + lr, (ks * 32 + g * 8) * 2));
                    sf = MFMA16x16x32(ak, aqA[ks], sf);
                }
                st[nf] = sf;
            }
            __builtin_amdgcn_s_setprio(0);
            const bool diag = (t == ntA - 1);
#pragma unroll
            for (int nf = 0; nf < 4; nf++)
#pragma unroll
                for (int rg = 0; rg < 4; rg++) {
                    float p = __builtin_amdgcn_exp2f(st[nf][rg]);
                    if (diag && (nf * 16 + g * 4 + rg > q_rel)) p = 0.f;
                    st[nf][rg] = p;
                }
#pragma unroll
            for (int nf = 0; nf < 4; nf++) {
                uint2 dw;
                dw.x = cvt_pk_bf2(st[nf][0], st[nf][1]);
                dw.y = cvt_pk_bf2(st[nf][2], st[nf][3]);
                *(uint2*)(pbaseA + swz128(lr, nf * 32 + g * 8)) = dw;
            }
        }

        // ---- phase 2: P-read + PV + ones-MFMA row-sum for B, then A ----
        {
            s16x8 pf[2];
#pragma unroll
            for (int ks = 0; ks < 2; ks++)
                pf[ks] = *(const s16x8*)(pbaseB + swz128(lr, ks * 64 + g * 16));
            __builtin_amdgcn_s_setprio(1);
#pragma unroll
            for (int nf = 0; nf < 4; nf++) {
#pragma unroll
                for (int ks = 0; ks < 2; ks++) {
                    s16x8 bv = *(const s16x8*)(vbase + swz128(nf * 16 + lr, ks * 64 + g * 16));
                    oB[nf] = MFMA16x16x32(pf[ks], bv, oB[nf]);
                }
            }
            lsumB = MFMA16x16x32(pf[0], vone, lsumB);
            lsumB = MFMA16x16x32(pf[1], vone, lsumB);
            __builtin_amdgcn_s_setprio(0);
        }
        if (actA) {
            s16x8 pf[2];
#pragma unroll
            for (int ks = 0; ks < 2; ks++)
                pf[ks] = *(const s16x8*)(pbaseA + swz128(lr, ks * 64 + g * 16));
            __builtin_amdgcn_s_setprio(1);
#pragma unroll
            for (int nf = 0; nf < 4; nf++) {
#pragma unroll
                for (int ks = 0; ks < 2; ks++) {
                    s16x8 bv = *(const s16x8*)(vbase + swz128(nf * 16 + lr, ks * 64 + g * 16));
                    oA[nf] = MFMA16x16x32(pf[ks], bv, oA[nf]);
                }
            }
            lsumA = MFMA16x16x32(pf[0], vone, lsumA);
            lsumA = MFMA16x16x32(pf[1], vone, lsumA);
            __builtin_amdgcn_s_setprio(0);
        }

        // stage tile t+1 into the other buffer; issue loads for t+2
        if (t + 1 < ntB) {
            char* kn = smem + ((t + 1) & 1) * 8192;
            char* vn = smem + 16384 + ((t + 1) & 1) * 8192;
            *(s16x8*)(kn + swz128(krow, kcol)) = k0;
            *(s16x8*)(kn + swz128(krow, kcol + 16)) = k1;
            *(s16x8*)(vn + swz128(krow, kcol)) = v0;
            *(s16x8*)(vn + swz128(krow, kcol + 16)) = v1;
            if (t + 2 < ntB) {
                const unsigned short* pk = pkBase + (size_t)(t + 2) * 64 * 1536;
                k0 = *(const s16x8*)(pk);
                k1 = *(const s16x8*)(pk + 8);
                const unsigned short* pv = pvBase + (t + 2) * 64;
                v0 = *(const s16x8*)(pv);
                v1 = *(const s16x8*)(pv + 8);
            }
        }
        BARRIER_LGKM();              // single barrier per tile
    }

    // epilogue: lsum[rg] is the row-sum for q = wid*16+g*4+rg — same slot as o
#pragma unroll
    for (int which = 0; which < 2; which++) {
        const f32x4 lsum = which ? lsumB : lsumA;
        const int q0 = which ? q0B : q0A;
        f32x4* o = which ? oB : oA;
        float linv_q[4];
#pragma unroll
        for (int rg = 0; rg < 4; rg++) linv_q[rg] = 1.0f / lsum[rg];
#pragma unroll
        for (int nf = 0; nf < 4; nf++) {
#pragma unroll
            for (int rg = 0; rg < 4; rg++) {
                int row = b * T + q0 + wid * 16 + g * 4 + rg;
                int col = h * 64 + nf * 16 + lr;
                y[(size_t)row * 768 + col] = f2bf(o[nf][rg] * linv_q[rg]);
            }
        }
    }
}

extern "C" void kernel_launch(void* const* d_in, const int* in_sizes, int n_in,
                              void* d_out, int out_size, void* d_ws, size_t ws_size,
                              hipStream_t stream) {
    const float* x      = (const float*)d_in[0];
    const float* w_attn = (const float*)d_in[1];
    const float* b_attn = (const float*)d_in[2];
    const float* w_proj = (const float*)d_in[3];
    const float* b_proj = (const float*)d_in[4];

    char* ws = (char*)d_ws;
    unsigned short* qk  = (unsigned short*)(ws);
    unsigned short* Vt  = (unsigned short*)(ws + 25165824);
    unsigned short* wTa = (unsigned short*)(ws + 37748736);
    unsigned short* wTp = (unsigned short*)(ws + 41287680);

    const bool big = ws_size >= (size_t)55050240;
    unsigned short* xb = (unsigned short*)d_out;
    unsigned short* yb = big ? (unsigned short*)(ws + 42467328)
                             : (unsigned short*)((char*)d_out + 12582912);
    float* projOut = big ? (float*)d_out : (float*)ws;

    prologue_kernel<<<4352, 256, 0, stream>>>(x, xb, w_attn, wTa, w_proj, wTp);

    // qscale = 0.125 * log2(e): softmax scale and exp->exp2 folded into Q
    gemm_bt<true><<<1152, 256, 0, stream>>>(xb, wTa, b_attn, (void*)qk, Vt,
                                            8192, 2304, 768, 1536, 768, 0.1803368801111244f);
    attn_kernel<<<768, 256, 0, stream>>>(qk, Vt, yb);
    gemm_bt<false><<<384, 256, 0, stream>>>(yb, wTp, b_proj, (void*)projOut, nullptr,
                                            8192, 768, 768, 768, 0, 1.0f);
    if (!big)
        hipMemcpyAsync(d_out, projOut, 25165824, hipMemcpyDeviceToDevice, stream);
}

// Round 18
// 117.856 us; speedup vs baseline: 1.0696x; 1.0409x over previous
//
#include <hip/hip_runtime.h>
#include <hip/hip_bf16.h>

using f32x4 = __attribute__((ext_vector_type(4))) float;
using s16x8 = __attribute__((ext_vector_type(8))) short;

#define MFMA16x16x32(a, b, c) __builtin_amdgcn_mfma_f32_16x16x32_bf16((a), (b), (c), 0, 0, 0)

#define AS_G(p) ((const __attribute__((address_space(1))) void*)(p))
#define AS_L(p) ((__attribute__((address_space(3))) void*)(p))

// barrier with LDS-visibility only: does NOT drain vmcnt
#define BARRIER_LGKM() do { \
    asm volatile("s_waitcnt lgkmcnt(0)" ::: "memory"); \
    __builtin_amdgcn_s_barrier(); \
} while (0)

static __device__ __forceinline__ unsigned short f2bf(float f) {
    unsigned int u = __float_as_uint(f);
    u = (u + 0x7fffu + ((u >> 16) & 1u)) >> 16;
    return (unsigned short)u;
}
static __device__ __forceinline__ unsigned int cvt_pk_bf2(float lo, float hi) {
    unsigned int r;
    asm("v_cvt_pk_bf16_f32 %0, %1, %2" : "=v"(r) : "v"(lo), "v"(hi));
    return r;
}
// swizzled byte offsets — used IDENTICALLY on write and read sides
static __device__ __forceinline__ int swz128(int r, int c) { return (r * 128 + c) ^ ((r & 7) << 4); }
static __device__ __forceinline__ int swz256v(int r, int c) { return (r * 256 + c) ^ ((r & 7) << 4); }

// ---- fused prologue: x->bf16 convert + both weight transposes ----
__global__ __launch_bounds__(256)
void prologue_kernel(const float* __restrict__ x, unsigned short* __restrict__ xb,
                     const float* __restrict__ w_attn, unsigned short* __restrict__ wTa,
                     const float* __restrict__ w_proj, unsigned short* __restrict__ wTp) {
    __shared__ float tile[32][33];
    const int bid = blockIdx.x, tid = threadIdx.x;
    if (bid < 2048) {
        const int n = 8192 * 768;
        int i = (bid * 256 + tid) * 4;
        const int stride = 2048 * 256 * 4;
        for (; i < n; i += stride) {
            float4 v = *(const float4*)(x + i);
            ushort4 o;
            o.x = f2bf(v.x); o.y = f2bf(v.y); o.z = f2bf(v.z); o.w = f2bf(v.w);
            *(ushort4*)(xb + i) = o;
        }
    } else {
        const float* w; unsigned short* wt; int K, N, bx, by;
        if (bid < 3776) {
            int id = bid - 2048; w = w_attn; wt = wTa; K = 768; N = 2304;
            bx = id % 72; by = id / 72;
        } else {
            int id = bid - 3776; w = w_proj; wt = wTp; K = 768; N = 768;
            bx = id % 24; by = id / 24;
        }
        const int tx = tid & 31, ty = tid >> 5;
        const int n0 = bx * 32, k0 = by * 32;
#pragma unroll
        for (int r = 0; r < 4; r++)
            tile[ty * 4 + r][tx] = w[(size_t)(k0 + ty * 4 + r) * N + n0 + tx];
        __syncthreads();
#pragma unroll
        for (int r = 0; r < 4; r++)
            wt[(size_t)(n0 + ty * 4 + r) * K + k0 + tx] = f2bf(tile[tx][ty * 4 + r]);
    }
}

// ---- GEMM: C[M,N] = A[M,K] * Bt[N,K]^T + bias ----
// BK=64 2-phase dbuf gload_lds (round-16 proven structure), XCD-clustered
// 1-D grid. V-region blocks (n0>=1536, block-uniform) store Vt via an LDS
// transpose bounce: coalesced 256B segments instead of scattered 8B stores
// (round-17 profile: WRITE_SIZE 46.5MB vs 37.6 expected = 8B-scatter
// amplification).
template <bool OUT_BF16>
__global__ __launch_bounds__(256, 2)
void gemm_bt(const unsigned short* __restrict__ A, const unsigned short* __restrict__ Bt,
             const float* __restrict__ bias, void* __restrict__ Cout,
             unsigned short* __restrict__ Vt,
             int M, int N, int K, int ldc, int qcols, float qscale) {
    __shared__ char smem[65536];
    const int tid = threadIdx.x, wid = tid >> 6, lane = tid & 63;
    const int g = lane >> 4, lr = lane & 15;
    const int nx = N >> 7;
    const int ypx = (M >> 7) >> 3;
    const int xcd = blockIdx.x & 7, ii = blockIdx.x >> 3;
    const int m0 = (xcd * ypx + ii / nx) * 128;
    const int n0 = (ii % nx) * 128;
    const int wm = wid >> 1, wn = wid & 1;

    f32x4 acc[4][4];
#pragma unroll
    for (int i = 0; i < 4; i++)
#pragma unroll
        for (int j = 0; j < 4; j++) acc[i][j] = f32x4{0.f, 0.f, 0.f, 0.f};

    const int rbase = lane >> 3;
    const int cSw = ((lane & 7) << 4) ^ (rbase << 4);

    auto STAGE = [&](int buf, int kt) {
        char* base = smem + buf * 32768;
#pragma unroll
        for (int ww = 0; ww < 4; ww++) {
            int w = wid * 4 + ww;
            int r = w * 8 + rbase;
            const unsigned short* srcA = A + (size_t)(m0 + r) * K + kt + (cSw >> 1);
            __builtin_amdgcn_global_load_lds(AS_G(srcA), AS_L(base + w * 1024), 16, 0, 0);
            const unsigned short* srcB = Bt + (size_t)(n0 + r) * K + kt + (cSw >> 1);
            __builtin_amdgcn_global_load_lds(AS_G(srcB), AS_L(base + 16384 + w * 1024), 16, 0, 0);
        }
    };

    const int nk = K >> 6;
    STAGE(0, 0);

    for (int t = 0; t < nk; t++) {
        if (t + 1 < nk) {
            STAGE((t + 1) & 1, (t + 1) << 6);
            asm volatile("s_waitcnt vmcnt(8)" ::: "memory");   // t's 8 loads done
        } else {
            asm volatile("s_waitcnt vmcnt(0)" ::: "memory");
        }
        __builtin_amdgcn_s_barrier();
        char* cbase = smem + (t & 1) * 32768;
#pragma unroll
        for (int ks = 0; ks < 2; ks++) {
            s16x8 af[4], bfr[4];
#pragma unroll
            for (int i = 0; i < 4; i++)
                af[i] = *(const s16x8*)(cbase + swz128(wm * 64 + i * 16 + lr, ks * 64 + g * 16));
#pragma unroll
            for (int j = 0; j < 4; j++)
                bfr[j] = *(const s16x8*)(cbase + 16384 + swz128(wn * 64 + j * 16 + lr, ks * 64 + g * 16));
#pragma unroll
            for (int i = 0; i < 4; i++)
#pragma unroll
                for (int j = 0; j < 4; j++)
                    acc[i][j] = MFMA16x16x32(af[i], bfr[j], acc[i][j]);
        }
        BARRIER_LGKM();
    }

    if (Vt != nullptr && n0 >= 1536) {
        // V block: bounce C-tile through LDS transposed [128 d][128 t], then
        // store coalesced (16 lanes cover one d-row's 256B segment).
#pragma unroll
        for (int j = 0; j < 4; j++) {
            int dl = wn * 64 + j * 16 + lr;
            float bv = bias[n0 + dl];
#pragma unroll
            for (int i = 0; i < 4; i++) {
                int tl = wm * 64 + i * 16 + g * 4;
                ushort4 o4;
                o4.x = f2bf(acc[i][j][0] + bv);
                o4.y = f2bf(acc[i][j][1] + bv);
                o4.z = f2bf(acc[i][j][2] + bv);
                o4.w = f2bf(acc[i][j][3] + bv);
                *(ushort4*)(smem + swz256v(dl, tl * 2)) = o4;
            }
        }
        __syncthreads();
        const int bb = m0 >> 11, t0 = m0 & 2047;
#pragma unroll
        for (int it = 0; it < 8; it++) {
            int dl = it * 16 + wid * 4 + g;
            int dg = (n0 - 1536) + dl;
            int hh = dg >> 6, dd = dg & 63;
            s16x8 v = *(const s16x8*)(smem + swz256v(dl, lr * 16));
            *(s16x8*)(Vt + ((((size_t)bb * 12 + hh) * 64 + dd) << 11) + t0 + lr * 8) = v;
        }
    } else {
#pragma unroll
        for (int j = 0; j < 4; j++) {
            int c = n0 + wn * 64 + j * 16 + lr;
            float bv = bias[c];
            float cscale = (c < qcols) ? qscale : 1.0f;
#pragma unroll
            for (int i = 0; i < 4; i++) {
#pragma unroll
                for (int rg = 0; rg < 4; rg++) {
                    int r = m0 + wm * 64 + i * 16 + g * 4 + rg;
                    float val = (acc[i][j][rg] + bv) * cscale;
                    if constexpr (OUT_BF16)
                        ((unsigned short*)Cout)[(size_t)r * ldc + c] = f2bf(val);
                    else
                        ((float*)Cout)[(size_t)r * ldc + c] = val;
                }
            }
        }
    }
}

// ---- causal flash attention: EXACT round-14 body (best: 49.4 us) ----
__global__ __launch_bounds__(256, 2)
void attn_kernel(const unsigned short* __restrict__ qk, const unsigned short* __restrict__ Vt,
                 unsigned short* __restrict__ y) {
    __shared__ char smem[49152];
    const int tid = threadIdx.x, wid = tid >> 6, lane = tid & 63;
    const int g = lane >> 4, lr = lane & 15;
    const int T = 2048;

    const int s = blockIdx.x;
    const int xcd = s & 7, i = s >> 3;
    const int grp = xcd * 6 + (i >> 4);
    const int qpi = i & 15;
    const int h = grp % 12, b = grp / 12;
    const int qtA = qpi, qtB = 31 - qpi;
    const int q0A = qtA * 64, q0B = qtB * 64;

    const int krow = tid >> 2;
    const int kcol = (tid & 3) * 32;

    s16x8 vone;
#pragma unroll
    for (int e = 0; e < 8; e++) vone[e] = (short)0x3F80;   // bf16 1.0

    const unsigned short* qrowA = qk + (size_t)(b * T + q0A + wid * 16 + lr) * 1536 + h * 64;
    const unsigned short* qrowB = qk + (size_t)(b * T + q0B + wid * 16 + lr) * 1536 + h * 64;
    s16x8 aqA[2], aqB[2];
    aqA[0] = *(const s16x8*)(qrowA + g * 8);
    aqA[1] = *(const s16x8*)(qrowA + 32 + g * 8);
    aqB[0] = *(const s16x8*)(qrowB + g * 8);
    aqB[1] = *(const s16x8*)(qrowB + 32 + g * 8);

    f32x4 oA[4], oB[4], lsumA, lsumB;
#pragma unroll
    for (int r = 0; r < 4; r++) { oA[r] = f32x4{0.f, 0.f, 0.f, 0.f}; oB[r] = f32x4{0.f, 0.f, 0.f, 0.f}; }
    lsumA = f32x4{0.f, 0.f, 0.f, 0.f};
    lsumB = f32x4{0.f, 0.f, 0.f, 0.f};

    const unsigned short* pkBase = qk + (size_t)(b * T + krow) * 1536 + 768 + h * 64 + (kcol >> 1);
    const unsigned short* pvBase = Vt + ((((size_t)b * 12 + h) * 64 + krow) << 11) + (kcol >> 1);

    const int ntA = qtA + 1, ntB = qtB + 1;

    // prologue: load tile 0 -> buf0; issue loads for tile 1
    s16x8 k0 = *(const s16x8*)(pkBase);
    s16x8 k1 = *(const s16x8*)(pkBase + 8);
    s16x8 v0 = *(const s16x8*)(pvBase);
    s16x8 v1 = *(const s16x8*)(pvBase + 8);
    *(s16x8*)(smem + swz128(krow, kcol)) = k0;
    *(s16x8*)(smem + swz128(krow, kcol + 16)) = k1;
    *(s16x8*)(smem + 16384 + swz128(krow, kcol)) = v0;
    *(s16x8*)(smem + 16384 + swz128(krow, kcol + 16)) = v1;
    if (ntB > 1) {
        const unsigned short* pk = pkBase + (size_t)64 * 1536;
        k0 = *(const s16x8*)(pk);
        k1 = *(const s16x8*)(pk + 8);
        const unsigned short* pv = pvBase + 64;
        v0 = *(const s16x8*)(pv);
        v1 = *(const s16x8*)(pv + 8);
    }
    BARRIER_LGKM();

    char* const pbaseB = smem + 32768 + wid * 2048;
    char* const pbaseA = smem + 40960 + wid * 2048;
    const int q_rel = wid * 16 + lr;

    for (int t = 0; t < ntB; t++) {
        char* kbase = smem + (t & 1) * 8192;
        char* vbase = smem + 16384 + (t & 1) * 8192;
        const bool actA = (t < ntA);

        // ---- phase 1: QK^T + exp + P-write for B, then A (separate buffers) ----
        {
            f32x4 st[4];
            __builtin_amdgcn_s_setprio(1);
#pragma unroll
            for (int nf = 0; nf < 4; nf++) {
                f32x4 sf = f32x4{0.f, 0.f, 0.f, 0.f};
#pragma unroll
                for (int ks = 0; ks < 2; ks++) {
                    s16x8 ak = *(const s16x8*)(kbase + swz128(nf * 16 + lr, (ks * 32 + g * 8) * 2));
                    sf = MFMA16x16x32(ak, aqB[ks], sf);
                }
                st[nf] = sf;
            }
            __builtin_amdgcn_s_setprio(0);
            const bool diag = (t == ntB - 1);
#pragma unroll
            for (int nf = 0; nf < 4; nf++)
#pragma unroll
                for (int rg = 0; rg < 4; rg++) {
                    float p = __builtin_amdgcn_exp2f(st[nf][rg]);
                    if (diag && (nf * 16 + g * 4 + rg > q_rel)) p = 0.f;
                    st[nf][rg] = p;
                }
#pragma unroll
            for (int nf = 0; nf < 4; nf++) {
                uint2 dw;
                dw.x = cvt_pk_bf2(st[nf][0], st[nf][1]);
                dw.y = cvt_pk_bf2(st[nf][2], st[nf][3]);
                *(uint2*)(pbaseB + swz128(lr, nf * 32 + g * 8)) = dw;
            }
        }
        if (actA) {
            f32x4 st[4];
            __builtin_amdgcn_s_setprio(1);
#pragma unroll
            for (int nf = 0; nf < 4; nf++) {
                f32x4 sf = f32x4{0.f, 0.f, 0.f, 0.f};
#pragma unroll
                for (int ks = 0; ks < 2; ks++) {
                    s16x8 ak = *(const s16x8*)(kbase + swz128(nf * 16 + lr, (ks * 32 + g * 8) * 2));
                    sf = MFMA16x16x32(ak, aqA[ks], sf);
                }
                st[nf] = sf;
            }
            __builtin_amdgcn_s_setprio(0);
            const bool diag = (t == ntA - 1);
#pragma unroll
            for (int nf = 0; nf < 4; nf++)
#pragma unroll
                for (int rg = 0; rg < 4; rg++) {
                    float p = __builtin_amdgcn_exp2f(st[nf][rg]);
                    if (diag && (nf * 16 + g * 4 + rg > q_rel)) p = 0.f;
                    st[nf][rg] = p;
                }
#pragma unroll
            for (int nf = 0; nf < 4; nf++) {
                uint2 dw;
                dw.x = cvt_pk_bf2(st[nf][0], st[nf][1]);
                dw.y = cvt_pk_bf2(st[nf][2], st[nf][3]);
                *(uint2*)(pbaseA + swz128(lr, nf * 32 + g * 8)) = dw;
            }
        }

        // ---- phase 2: P-read + PV + ones-MFMA row-sum for B, then A ----
        {
            s16x8 pf[2];
#pragma unroll
            for (int ks = 0; ks < 2; ks++)
                pf[ks] = *(const s16x8*)(pbaseB + swz128(lr, ks * 64 + g * 16));
            __builtin_amdgcn_s_setprio(1);
#pragma unroll
            for (int nf = 0; nf < 4; nf++) {
#pragma unroll
                for (int ks = 0; ks < 2; ks++) {
                    s16x8 bv = *(const s16x8*)(vbase + swz128(nf * 16 + lr, ks * 64 + g * 16));
                    oB[nf] = MFMA16x16x32(pf[ks], bv, oB[nf]);
                }
            }
            lsumB = MFMA16x16x32(pf[0], vone, lsumB);
            lsumB = MFMA16x16x32(pf[1], vone, lsumB);
            __builtin_amdgcn_s_setprio(0);
        }
        if (actA) {
            s16x8 pf[2];
#pragma unroll
            for (int ks = 0; ks < 2; ks++)
                pf[ks] = *(const s16x8*)(pbaseA + swz128(lr, ks * 64 + g * 16));
            __builtin_amdgcn_s_setprio(1);
#pragma unroll
            for (int nf = 0; nf < 4; nf++) {
#pragma unroll
                for (int ks = 0; ks < 2; ks++) {
                    s16x8 bv = *(const s16x8*)(vbase + swz128(nf * 16 + lr, ks * 64 + g * 16));
                    oA[nf] = MFMA16x16x32(pf[ks], bv, oA[nf]);
                }
            }
            lsumA = MFMA16x16x32(pf[0], vone, lsumA);
            lsumA = MFMA16x16x32(pf[1], vone, lsumA);
            __builtin_amdgcn_s_setprio(0);
        }

        // stage tile t+1 into the other buffer; issue loads for t+2
        if (t + 1 < ntB) {
            char* kn = smem + ((t + 1) & 1) * 8192;
            char* vn = smem + 16384 + ((t + 1) & 1) * 8192;
            *(s16x8*)(kn + swz128(krow, kcol)) = k0;
            *(s16x8*)(kn + swz128(krow, kcol + 16)) = k1;
            *(s16x8*)(vn + swz128(krow, kcol)) = v0;
            *(s16x8*)(vn + swz128(krow, kcol + 16)) = v1;
            if (t + 2 < ntB) {
                const unsigned short* pk = pkBase + (size_t)(t + 2) * 64 * 1536;
                k0 = *(const s16x8*)(pk);
                k1 = *(const s16x8*)(pk + 8);
                const unsigned short* pv = pvBase + (t + 2) * 64;
                v0 = *(const s16x8*)(pv);
                v1 = *(const s16x8*)(pv + 8);
            }
        }
        BARRIER_LGKM();              // single barrier per tile
    }

    // epilogue: lsum[rg] is the row-sum for q = wid*16+g*4+rg — same slot as o
#pragma unroll
    for (int which = 0; which < 2; which++) {
        const f32x4 lsum = which ? lsumB : lsumA;
        const int q0 = which ? q0B : q0A;
        f32x4* o = which ? oB : oA;
        float linv_q[4];
#pragma unroll
        for (int rg = 0; rg < 4; rg++) linv_q[rg] = 1.0f / lsum[rg];
#pragma unroll
        for (int nf = 0; nf < 4; nf++) {
#pragma unroll
            for (int rg = 0; rg < 4; rg++) {
                int row = b * T + q0 + wid * 16 + g * 4 + rg;
                int col = h * 64 + nf * 16 + lr;
                y[(size_t)row * 768 + col] = f2bf(o[nf][rg] * linv_q[rg]);
            }
        }
    }
}

extern "C" void kernel_launch(void* const* d_in, const int* in_sizes, int n_in,
                              void* d_out, int out_size, void* d_ws, size_t ws_size,
                              hipStream_t stream) {
    const float* x      = (const float*)d_in[0];
    const float* w_attn = (const float*)d_in[1];
    const float* b_attn = (const float*)d_in[2];
    const float* w_proj = (const float*)d_in[3];
    const float* b_proj = (const float*)d_in[4];

    char* ws = (char*)d_ws;
    unsigned short* qk  = (unsigned short*)(ws);
    unsigned short* Vt  = (unsigned short*)(ws + 25165824);
    unsigned short* wTa = (unsigned short*)(ws + 37748736);
    unsigned short* wTp = (unsigned short*)(ws + 41287680);

    const bool big = ws_size >= (size_t)55050240;
    unsigned short* xb = (unsigned short*)d_out;
    unsigned short* yb = big ? (unsigned short*)(ws + 42467328)
                             : (unsigned short*)((char*)d_out + 12582912);
    float* projOut = big ? (float*)d_out : (float*)ws;

    prologue_kernel<<<4352, 256, 0, stream>>>(x, xb, w_attn, wTa, w_proj, wTp);

    // qscale = 0.125 * log2(e): softmax scale and exp->exp2 folded into Q
    gemm_bt<true><<<1152, 256, 0, stream>>>(xb, wTa, b_attn, (void*)qk, Vt,
                                            8192, 2304, 768, 1536, 768, 0.1803368801111244f);
    attn_kernel<<<768, 256, 0, stream>>>(qk, Vt, yb);
    gemm_bt<false><<<384, 256, 0, stream>>>(yb, wTp, b_proj, (void*)projOut, nullptr,
                                            8192, 768, 768, 768, 0, 1.0f);
    if (!big)
        hipMemcpyAsync(d_out, projOut, 25165824, hipMemcpyDeviceToDevice, stream);
}